// Round 2
// baseline (871.174 us; speedup 1.0000x reference)
//
#include <hip/hip_runtime.h>

typedef short bf16x8 __attribute__((ext_vector_type(8)));
typedef float f32x4  __attribute__((ext_vector_type(4)));

#define LSTR 296  // LDS row stride in ushorts: 288 data + 8 pad (stride % 32 dwords = 20 -> 2-way = free)

__device__ __forceinline__ unsigned short f2bf(float f) {
    unsigned u = __float_as_uint(f);
    return (unsigned short)((u + 0x7FFFu + ((u >> 16) & 1u)) >> 16);  // RNE
}

// One block per spatial location (h,w): GEMM M=64(b) x N=64(co) x K=576(ci*9+ky*3+kx).
// A (x-patch) staged in LDS as bf16 in two K-halves (ci 0..31, 32..63).
// B (weights) streamed straight from global into registers (contiguous per co), nontemporal.
__global__ __launch_bounds__(256, 4)
void lc_mfma(const float* __restrict__ x, const float* __restrict__ wt,
             float* __restrict__ out) {
    __shared__ __align__(16) unsigned short A[64 * LSTR];

    const int bid = blockIdx.x;
    const int swz = (bid & 7) * 512 + (bid >> 3);   // bijective XCD-contiguous remap (4096 % 8 == 0)
    const int h   = swz >> 6;
    const int wq  = swz & 63;

    const int t    = threadIdx.x;
    const int lane = t & 63;
    const int wv   = t >> 6;                        // wave id 0..3 -> co slice

    const float* wloc = wt + (size_t)((h << 6) + wq) * 36864;  // 64*64*9 floats per location
    const int co = (wv << 4) + (lane & 15);
    const int kg = lane >> 4;                        // k-group 0..3
    const float* wrow = wloc + co * 576 + (kg << 3);

    f32x4 acc[4] = {{0.f,0.f,0.f,0.f},{0.f,0.f,0.f,0.f},
                    {0.f,0.f,0.f,0.f},{0.f,0.f,0.f,0.f}};

    const int cil = t & 31;   // ci within half
    const int bro = t >> 5;   // 0..7

    for (int hs = 0; hs < 2; ++hs) {
        const int kbase = hs * 288;

        // early weight prefetch for steps 0,1 (independent of LDS staging below)
        f32x4 pb[3][2];
        pb[0][0] = __builtin_nontemporal_load((const f32x4*)(wrow + kbase + 0));
        pb[0][1] = __builtin_nontemporal_load((const f32x4*)(wrow + kbase + 4));
        pb[1][0] = __builtin_nontemporal_load((const f32x4*)(wrow + kbase + 32));
        pb[1][1] = __builtin_nontemporal_load((const f32x4*)(wrow + kbase + 36));

        // ---- stage A-half: ci in [hs*32, hs*32+32), all 64 b ----
        {
            const int ci = (hs << 5) + cil;
            for (int p = 0; p < 8; ++p) {
                const int b = (p << 3) + bro;
                const float* xb = x + ((size_t)((b << 6) + ci) << 12);
                unsigned short* dst = &A[b * LSTR + cil * 9];
                #pragma unroll
                for (int dy = 0; dy < 3; ++dy) {
                    const int y = h + dy - 1;
                    const bool yok = (unsigned)y < 64u;
                    #pragma unroll
                    for (int dx = 0; dx < 3; ++dx) {
                        const int xx = wq + dx - 1;
                        float v = 0.f;
                        if (yok && (unsigned)xx < 64u) v = xb[(y << 6) + xx];
                        dst[dy * 3 + dx] = f2bf(v);
                    }
                }
            }
        }
        __syncthreads();

        // ---- 9 MFMA k-steps of 32 over this half; 2-step register lookahead on B ----
        #pragma unroll
        for (int ks = 0; ks < 9; ++ks) {
            const int cur = ks % 3;
            const int nxt = (ks + 2) % 3;
            if (ks < 7) {
                const float* np = wrow + kbase + (ks + 2) * 32;
                pb[nxt][0] = __builtin_nontemporal_load((const f32x4*)(np));
                pb[nxt][1] = __builtin_nontemporal_load((const f32x4*)(np + 4));
            }
            const f32x4 lo = pb[cur][0], hi = pb[cur][1];
            bf16x8 bf;
            bf[0] = (short)f2bf(lo[0]); bf[1] = (short)f2bf(lo[1]);
            bf[2] = (short)f2bf(lo[2]); bf[3] = (short)f2bf(lo[3]);
            bf[4] = (short)f2bf(hi[0]); bf[5] = (short)f2bf(hi[1]);
            bf[6] = (short)f2bf(hi[2]); bf[7] = (short)f2bf(hi[3]);
            const int kk = (ks << 5) + (kg << 3);
            #pragma unroll
            for (int mt = 0; mt < 4; ++mt) {
                const bf16x8 af = *(const bf16x8*)&A[((mt << 4) + (lane & 15)) * LSTR + kk];
                acc[mt] = __builtin_amdgcn_mfma_f32_16x16x32_bf16(af, bf, acc[mt], 0, 0, 0);
            }
        }
        __syncthreads();
    }

    // epilogue: D frag: row=(lane>>4)*4+j (b within m-tile), col=lane&15 (co within n-tile)
    const int rg = lane >> 4;
    #pragma unroll
    for (int mt = 0; mt < 4; ++mt) {
        #pragma unroll
        for (int j = 0; j < 4; ++j) {
            const int b = (mt << 4) + (rg << 2) + j;
            out[(size_t)((b << 6) + co) * 4096 + (h << 6) + wq] = fmaxf(acc[mt][j], 0.f);
        }
    }
}

extern "C" void kernel_launch(void* const* d_in, const int* in_sizes, int n_in,
                              void* d_out, int out_size, void* d_ws, size_t ws_size,
                              hipStream_t stream) {
    const float* x  = (const float*)d_in[0];
    const float* wt = (const float*)d_in[1];
    float* out = (float*)d_out;
    hipLaunchKernelGGL(lc_mfma, dim3(4096), dim3(256), 0, stream, x, wt, out);
}

// Round 3
// 202.637 us; speedup vs baseline: 4.2992x; 4.2992x over previous
//
#include <hip/hip_runtime.h>

typedef short bf16x8 __attribute__((ext_vector_type(8)));
typedef float f32x4  __attribute__((ext_vector_type(4)));
typedef unsigned short u16x4 __attribute__((ext_vector_type(4)));

#define LSTR 296  // LDS row stride in ushorts: 288 data + 8 pad

__device__ __forceinline__ unsigned short f2bf(float f) {
    unsigned u = __float_as_uint(f);
    return (unsigned short)((u + 0x7FFFu + ((u >> 16) & 1u)) >> 16);  // RNE
}

// ---- Kernel 1: x[bc][hw] f32 -> xT[hw][bc] bf16 (4096x4096 transpose) ----
__global__ __launch_bounds__(256)
void transpose_in(const float* __restrict__ x, unsigned short* __restrict__ xT) {
    __shared__ float tile[64][65];
    const int t  = threadIdx.x;
    const int tr = blockIdx.x >> 6, tc = blockIdx.x & 63;
    const int r0 = tr << 6, c0 = tc << 6;        // r: bc rows, c: hw cols
    const int cc = (t & 15) << 2;
    #pragma unroll
    for (int q = 0; q < 4; ++q) {
        const int rr = (t >> 4) + (q << 4);
        const f32x4 v = __builtin_nontemporal_load(
            (const f32x4*)&x[(size_t)(r0 + rr) * 4096 + c0 + cc]);
        tile[rr][cc + 0] = v[0]; tile[rr][cc + 1] = v[1];
        tile[rr][cc + 2] = v[2]; tile[rr][cc + 3] = v[3];
    }
    __syncthreads();
    #pragma unroll
    for (int q = 0; q < 4; ++q) {
        const int rr = (t >> 4) + (q << 4);      // hw within tile
        u16x4 o;
        o[0] = f2bf(tile[cc + 0][rr]); o[1] = f2bf(tile[cc + 1][rr]);
        o[2] = f2bf(tile[cc + 2][rr]); o[3] = f2bf(tile[cc + 3][rr]);
        *(u16x4*)&xT[(size_t)(c0 + rr) * 4096 + r0 + cc] = o;
    }
}

// ---- Kernel 3: outT[hw][bc] f32 -> out[bc][hw] f32 ----
__global__ __launch_bounds__(256)
void transpose_out(const float* __restrict__ src, float* __restrict__ dst) {
    __shared__ float tile[64][65];
    const int t  = threadIdx.x;
    const int tr = blockIdx.x >> 6, tc = blockIdx.x & 63;
    const int r0 = tr << 6, c0 = tc << 6;        // r: hw rows, c: bc cols
    const int cc = (t & 15) << 2;
    #pragma unroll
    for (int q = 0; q < 4; ++q) {
        const int rr = (t >> 4) + (q << 4);
        const f32x4 v = __builtin_nontemporal_load(
            (const f32x4*)&src[(size_t)(r0 + rr) * 4096 + c0 + cc]);
        tile[rr][cc + 0] = v[0]; tile[rr][cc + 1] = v[1];
        tile[rr][cc + 2] = v[2]; tile[rr][cc + 3] = v[3];
    }
    __syncthreads();
    #pragma unroll
    for (int q = 0; q < 4; ++q) {
        const int rr = (t >> 4) + (q << 4);      // bc within tile
        f32x4 o;
        o[0] = tile[cc + 0][rr]; o[1] = tile[cc + 1][rr];
        o[2] = tile[cc + 2][rr]; o[3] = tile[cc + 3][rr];
        *(f32x4*)&dst[(size_t)(c0 + rr) * 4096 + r0 + cc] = o;
    }
}

// ---- Kernel 2: main locally-connected GEMM. One block per (h,w). ----
// A (x-patch) staged into LDS from xT (coalesced); B (weights) streamed
// from global (contiguous per co, nontemporal). TO_OUTT: write contiguous
// outT[hw][b*64+co]; else scattered direct write (fallback).
template <bool TO_OUTT>
__global__ __launch_bounds__(256, 4)
void lc_main(const unsigned short* __restrict__ xT, const float* __restrict__ wt,
             float* __restrict__ outp) {
    __shared__ __align__(16) unsigned short A[64 * LSTR];

    const int bid = blockIdx.x;
    const int swz = (bid & 7) * 512 + (bid >> 3);   // XCD-contiguous bijective remap
    const int h   = swz >> 6;
    const int wq  = swz & 63;

    const int t    = threadIdx.x;
    const int lane = t & 63;
    const int wv   = t >> 6;

    const float* wloc = wt + (size_t)((h << 6) + wq) * 36864;
    const int co = (wv << 4) + (lane & 15);
    const int kg = lane >> 4;
    const float* wrow = wloc + co * 576 + (kg << 3);

    f32x4 acc[4] = {{0.f,0.f,0.f,0.f},{0.f,0.f,0.f,0.f},
                    {0.f,0.f,0.f,0.f},{0.f,0.f,0.f,0.f}};

    const int b_st = t >> 2;   // staging: b 0..63
    const int cig  = t & 3;    // staging: ci-group (8 ci each)

    for (int hs = 0; hs < 2; ++hs) {
        const int kbase = hs * 288;

        f32x4 pb[3][2];
        pb[0][0] = __builtin_nontemporal_load((const f32x4*)(wrow + kbase + 0));
        pb[0][1] = __builtin_nontemporal_load((const f32x4*)(wrow + kbase + 4));
        pb[1][0] = __builtin_nontemporal_load((const f32x4*)(wrow + kbase + 32));
        pb[1][1] = __builtin_nontemporal_load((const f32x4*)(wrow + kbase + 36));

        // ---- stage A-half from xT: per tap, [64b x 32ci] contiguous 4KB ----
        #pragma unroll
        for (int tap = 0; tap < 9; ++tap) {
            const int dy = tap / 3, dx = tap % 3;
            const int y  = h + dy - 1;
            const int xx = wq + dx - 1;
            bf16x8 v = {0,0,0,0,0,0,0,0};
            if ((unsigned)y < 64u && (unsigned)xx < 64u) {
                v = *(const bf16x8*)&xT[(size_t)((y << 6) + xx) * 4096
                                        + (b_st << 6) + (hs << 5) + (cig << 3)];
            }
            unsigned short* dst = &A[b_st * LSTR + cig * 72 + tap];
            #pragma unroll
            for (int j = 0; j < 8; ++j) dst[j * 9] = (unsigned short)v[j];
        }
        __syncthreads();

        // ---- 9 MFMA k-steps of 32; 2-step register lookahead on B ----
        #pragma unroll
        for (int ks = 0; ks < 9; ++ks) {
            const int cur = ks % 3;
            const int nxt = (ks + 2) % 3;
            if (ks < 7) {
                const float* np = wrow + kbase + (ks + 2) * 32;
                pb[nxt][0] = __builtin_nontemporal_load((const f32x4*)(np));
                pb[nxt][1] = __builtin_nontemporal_load((const f32x4*)(np + 4));
            }
            const f32x4 lo = pb[cur][0], hi = pb[cur][1];
            bf16x8 bf;
            bf[0] = (short)f2bf(lo[0]); bf[1] = (short)f2bf(lo[1]);
            bf[2] = (short)f2bf(lo[2]); bf[3] = (short)f2bf(lo[3]);
            bf[4] = (short)f2bf(hi[0]); bf[5] = (short)f2bf(hi[1]);
            bf[6] = (short)f2bf(hi[2]); bf[7] = (short)f2bf(hi[3]);
            const int kk = (ks << 5) + (kg << 3);
            #pragma unroll
            for (int mt = 0; mt < 4; ++mt) {
                const bf16x8 af = *(const bf16x8*)&A[((mt << 4) + (lane & 15)) * LSTR + kk];
                acc[mt] = __builtin_amdgcn_mfma_f32_16x16x32_bf16(af, bf, acc[mt], 0, 0, 0);
            }
        }
        __syncthreads();
    }

    const int rg = lane >> 4;
    if (TO_OUTT) {
        const size_t obase = (size_t)((h << 6) + wq) * 4096;
        #pragma unroll
        for (int mt = 0; mt < 4; ++mt) {
            #pragma unroll
            for (int j = 0; j < 4; ++j) {
                const int b = (mt << 4) + (rg << 2) + j;
                outp[obase + (b << 6) + co] = fmaxf(acc[mt][j], 0.f);
            }
        }
    } else {
        #pragma unroll
        for (int mt = 0; mt < 4; ++mt) {
            #pragma unroll
            for (int j = 0; j < 4; ++j) {
                const int b = (mt << 4) + (rg << 2) + j;
                outp[(size_t)((b << 6) + co) * 4096 + (h << 6) + wq] = fmaxf(acc[mt][j], 0.f);
            }
        }
    }
}

// ---- Fallback (round-2 proven kernel): direct gather from x ----
__global__ __launch_bounds__(256, 4)
void lc_mfma(const float* __restrict__ x, const float* __restrict__ wt,
             float* __restrict__ out) {
    __shared__ __align__(16) unsigned short A[64 * LSTR];
    const int bid = blockIdx.x;
    const int swz = (bid & 7) * 512 + (bid >> 3);
    const int h   = swz >> 6;
    const int wq  = swz & 63;
    const int t    = threadIdx.x;
    const int lane = t & 63;
    const int wv   = t >> 6;
    const float* wloc = wt + (size_t)((h << 6) + wq) * 36864;
    const int co = (wv << 4) + (lane & 15);
    const int kg = lane >> 4;
    const float* wrow = wloc + co * 576 + (kg << 3);
    f32x4 acc[4] = {{0.f,0.f,0.f,0.f},{0.f,0.f,0.f,0.f},
                    {0.f,0.f,0.f,0.f},{0.f,0.f,0.f,0.f}};
    const int cil = t & 31;
    const int bro = t >> 5;
    for (int hs = 0; hs < 2; ++hs) {
        const int kbase = hs * 288;
        f32x4 pb[3][2];
        pb[0][0] = __builtin_nontemporal_load((const f32x4*)(wrow + kbase + 0));
        pb[0][1] = __builtin_nontemporal_load((const f32x4*)(wrow + kbase + 4));
        pb[1][0] = __builtin_nontemporal_load((const f32x4*)(wrow + kbase + 32));
        pb[1][1] = __builtin_nontemporal_load((const f32x4*)(wrow + kbase + 36));
        {
            const int ci = (hs << 5) + cil;
            for (int p = 0; p < 8; ++p) {
                const int b = (p << 3) + bro;
                const float* xb = x + ((size_t)((b << 6) + ci) << 12);
                unsigned short* dst = &A[b * LSTR + cil * 9];
                #pragma unroll
                for (int dy = 0; dy < 3; ++dy) {
                    const int y = h + dy - 1;
                    const bool yok = (unsigned)y < 64u;
                    #pragma unroll
                    for (int dx = 0; dx < 3; ++dx) {
                        const int xx = wq + dx - 1;
                        float v = 0.f;
                        if (yok && (unsigned)xx < 64u) v = xb[(y << 6) + xx];
                        dst[dy * 3 + dx] = f2bf(v);
                    }
                }
            }
        }
        __syncthreads();
        #pragma unroll
        for (int ks = 0; ks < 9; ++ks) {
            const int cur = ks % 3;
            const int nxt = (ks + 2) % 3;
            if (ks < 7) {
                const float* np = wrow + kbase + (ks + 2) * 32;
                pb[nxt][0] = __builtin_nontemporal_load((const f32x4*)(np));
                pb[nxt][1] = __builtin_nontemporal_load((const f32x4*)(np + 4));
            }
            const f32x4 lo = pb[cur][0], hi = pb[cur][1];
            bf16x8 bf;
            bf[0] = (short)f2bf(lo[0]); bf[1] = (short)f2bf(lo[1]);
            bf[2] = (short)f2bf(lo[2]); bf[3] = (short)f2bf(lo[3]);
            bf[4] = (short)f2bf(hi[0]); bf[5] = (short)f2bf(hi[1]);
            bf[6] = (short)f2bf(hi[2]); bf[7] = (short)f2bf(hi[3]);
            const int kk = (ks << 5) + (kg << 3);
            #pragma unroll
            for (int mt = 0; mt < 4; ++mt) {
                const bf16x8 af = *(const bf16x8*)&A[((mt << 4) + (lane & 15)) * LSTR + kk];
                acc[mt] = __builtin_amdgcn_mfma_f32_16x16x32_bf16(af, bf, acc[mt], 0, 0, 0);
            }
        }
        __syncthreads();
    }
    const int rg = lane >> 4;
    #pragma unroll
    for (int mt = 0; mt < 4; ++mt) {
        #pragma unroll
        for (int j = 0; j < 4; ++j) {
            const int b = (mt << 4) + (rg << 2) + j;
            out[(size_t)((b << 6) + co) * 4096 + (h << 6) + wq] = fmaxf(acc[mt][j], 0.f);
        }
    }
}

extern "C" void kernel_launch(void* const* d_in, const int* in_sizes, int n_in,
                              void* d_out, int out_size, void* d_ws, size_t ws_size,
                              hipStream_t stream) {
    const float* x  = (const float*)d_in[0];
    const float* wt = (const float*)d_in[1];
    float* out = (float*)d_out;

    const size_t xT_bytes   = (size_t)4096 * 4096 * 2;  // 33.5 MB bf16
    const size_t outT_bytes = (size_t)4096 * 4096 * 4;  // 67 MB f32

    if (ws_size >= xT_bytes + outT_bytes) {
        unsigned short* xT = (unsigned short*)d_ws;
        float* outT = (float*)((char*)d_ws + xT_bytes);
        hipLaunchKernelGGL(transpose_in, dim3(4096), dim3(256), 0, stream, x, xT);
        hipLaunchKernelGGL((lc_main<true>), dim3(4096), dim3(256), 0, stream, xT, wt, outT);
        hipLaunchKernelGGL(transpose_out, dim3(4096), dim3(256), 0, stream, outT, out);
    } else if (ws_size >= xT_bytes) {
        unsigned short* xT = (unsigned short*)d_ws;
        hipLaunchKernelGGL(transpose_in, dim3(4096), dim3(256), 0, stream, x, xT);
        hipLaunchKernelGGL((lc_main<false>), dim3(4096), dim3(256), 0, stream, xT, wt, out);
    } else {
        hipLaunchKernelGGL(lc_mfma, dim3(4096), dim3(256), 0, stream, x, wt, out);
    }
}

// Round 4
// 200.238 us; speedup vs baseline: 4.3507x; 1.0120x over previous
//
#include <hip/hip_runtime.h>

typedef short bf16x8 __attribute__((ext_vector_type(8)));
typedef float f32x4  __attribute__((ext_vector_type(4)));
typedef unsigned short u16x4 __attribute__((ext_vector_type(4)));

#define LSTR 296  // LDS row stride in ushorts (288 data + 8 pad)

__device__ __forceinline__ unsigned short f2bf(float f) {
    unsigned u = __float_as_uint(f);
    return (unsigned short)((u + 0x7FFFu + ((u >> 16) & 1u)) >> 16);  // RNE
}

// ---- Kernel 1: x[bc][hw] f32 -> xT[hw][bc] bf16 ----
__global__ __launch_bounds__(256)
void transpose_in(const float* __restrict__ x, unsigned short* __restrict__ xT) {
    __shared__ float tile[64][65];
    const int t  = threadIdx.x;
    const int tr = blockIdx.x >> 6, tc = blockIdx.x & 63;
    const int r0 = tr << 6, c0 = tc << 6;        // r: bc rows, c: hw cols
    const int cc = (t & 15) << 2;
    #pragma unroll
    for (int q = 0; q < 4; ++q) {
        const int rr = (t >> 4) + (q << 4);
        const f32x4 v = __builtin_nontemporal_load(
            (const f32x4*)&x[(size_t)(r0 + rr) * 4096 + c0 + cc]);
        tile[rr][cc + 0] = v[0]; tile[rr][cc + 1] = v[1];
        tile[rr][cc + 2] = v[2]; tile[rr][cc + 3] = v[3];
    }
    __syncthreads();
    #pragma unroll
    for (int q = 0; q < 4; ++q) {
        const int rr = (t >> 4) + (q << 4);      // hw within tile
        u16x4 o;
        o[0] = f2bf(tile[cc + 0][rr]); o[1] = f2bf(tile[cc + 1][rr]);
        o[2] = f2bf(tile[cc + 2][rr]); o[3] = f2bf(tile[cc + 3][rr]);
        *(u16x4*)&xT[(size_t)(c0 + rr) * 4096 + r0 + cc] = o;
    }
}

// ---- Kernel 3: outT[hw][bc] bf16 -> out[bc][hw] f32 ----
__global__ __launch_bounds__(256)
void transpose_out_bf(const unsigned short* __restrict__ src, float* __restrict__ dst) {
    __shared__ unsigned short tile[64][66];      // stride 33 dw (odd) -> conflict-free cols
    const int t  = threadIdx.x;
    const int tr = blockIdx.x >> 6, tc = blockIdx.x & 63;
    const int r0 = tr << 6, c0 = tc << 6;        // r: hw rows, c: bc cols
    const int cc = (t & 15) << 2;
    #pragma unroll
    for (int q = 0; q < 4; ++q) {
        const int rr = (t >> 4) + (q << 4);
        const u16x4 v = __builtin_nontemporal_load(
            (const u16x4*)&src[(size_t)(r0 + rr) * 4096 + c0 + cc]);
        tile[rr][cc + 0] = v[0]; tile[rr][cc + 1] = v[1];
        tile[rr][cc + 2] = v[2]; tile[rr][cc + 3] = v[3];
    }
    __syncthreads();
    #pragma unroll
    for (int q = 0; q < 4; ++q) {
        const int rr = (t >> 4) + (q << 4);      // bc within tile
        f32x4 o;
        o[0] = __uint_as_float((unsigned)tile[cc + 0][rr] << 16);
        o[1] = __uint_as_float((unsigned)tile[cc + 1][rr] << 16);
        o[2] = __uint_as_float((unsigned)tile[cc + 2][rr] << 16);
        o[3] = __uint_as_float((unsigned)tile[cc + 3][rr] << 16);
        __builtin_nontemporal_store(o, (f32x4*)&dst[(size_t)(c0 + rr) * 4096 + r0 + cc]);
    }
}

// ---- Kernel 2: main locally-connected GEMM, one block per (h,w) ----
// 18-step continuous weight pipeline; A staged per K-half with async reg-staging:
// half1's xT loads are issued before half0's MFMA phase (T14).
__global__ __launch_bounds__(256, 4)
void lc_main(const unsigned short* __restrict__ xT, const float* __restrict__ wt,
             unsigned short* __restrict__ outT) {
    __shared__ __align__(16) unsigned short A[64 * LSTR];

    const int bid = blockIdx.x;
    const int swz = (bid & 7) * 512 + (bid >> 3);   // XCD-contiguous bijective remap
    const int h   = swz >> 6;
    const int wq  = swz & 63;

    const int t    = threadIdx.x;
    const int lane = t & 63;
    const int wv   = t >> 6;

    const float* wloc = wt + (size_t)((h << 6) + wq) * 36864;
    const int co = (wv << 4) + (lane & 15);
    const int kg = lane >> 4;
    const float* wrow = wloc + co * 576 + (kg << 3);   // + ks*32 per step, 0..17

    f32x4 acc[4] = {{0.f,0.f,0.f,0.f},{0.f,0.f,0.f,0.f},
                    {0.f,0.f,0.f,0.f},{0.f,0.f,0.f,0.f}};

    const int b_st = t >> 2;   // staging: b 0..63
    const int cig  = t & 3;    // staging: 8-ci group

    // weight lookahead: steps 0,1
    f32x4 pb[3][2];
    pb[0][0] = __builtin_nontemporal_load((const f32x4*)(wrow + 0));
    pb[0][1] = __builtin_nontemporal_load((const f32x4*)(wrow + 4));
    pb[1][0] = __builtin_nontemporal_load((const f32x4*)(wrow + 32));
    pb[1][1] = __builtin_nontemporal_load((const f32x4*)(wrow + 36));

    // xT loads for half 0
    bf16x8 xr[9];
    #pragma unroll
    for (int tap = 0; tap < 9; ++tap) {
        const int y  = h + tap / 3 - 1;
        const int xx = wq + tap % 3 - 1;
        bf16x8 v = {0,0,0,0,0,0,0,0};
        if ((unsigned)y < 64u && (unsigned)xx < 64u)
            v = *(const bf16x8*)&xT[(size_t)((y << 6) + xx) * 4096 + (b_st << 6) + (cig << 3)];
        xr[tap] = v;
    }
    // write half 0 to LDS (k = ci*9+tap within half)
    {
        unsigned short* dst = &A[b_st * LSTR + cig * 72];
        #pragma unroll
        for (int tap = 0; tap < 9; ++tap)
            #pragma unroll
            for (int j = 0; j < 8; ++j)
                dst[j * 9 + tap] = (unsigned short)xr[tap][j];
    }
    // issue half 1 xT loads now — in flight across the barrier + half0 MFMA
    #pragma unroll
    for (int tap = 0; tap < 9; ++tap) {
        const int y  = h + tap / 3 - 1;
        const int xx = wq + tap % 3 - 1;
        bf16x8 v = {0,0,0,0,0,0,0,0};
        if ((unsigned)y < 64u && (unsigned)xx < 64u)
            v = *(const bf16x8*)&xT[(size_t)((y << 6) + xx) * 4096 + (b_st << 6) + 32 + (cig << 3)];
        xr[tap] = v;
    }
    __syncthreads();

    // ---- 18 continuous k-steps of 32; LDS swap between step 8 and 9 ----
    #pragma unroll
    for (int ks = 0; ks < 18; ++ks) {
        if (ks == 9) {
            __syncthreads();   // all waves done reading half0
            unsigned short* dst = &A[b_st * LSTR + cig * 72];
            #pragma unroll
            for (int tap = 0; tap < 9; ++tap)
                #pragma unroll
                for (int j = 0; j < 8; ++j)
                    dst[j * 9 + tap] = (unsigned short)xr[tap][j];
            __syncthreads();
        }
        if (ks < 16) {
            const float* np = wrow + (ks + 2) * 32;
            pb[(ks + 2) % 3][0] = __builtin_nontemporal_load((const f32x4*)(np));
            pb[(ks + 2) % 3][1] = __builtin_nontemporal_load((const f32x4*)(np + 4));
        }
        const f32x4 lo = pb[ks % 3][0], hi = pb[ks % 3][1];
        bf16x8 bf;
        bf[0] = (short)f2bf(lo[0]); bf[1] = (short)f2bf(lo[1]);
        bf[2] = (short)f2bf(lo[2]); bf[3] = (short)f2bf(lo[3]);
        bf[4] = (short)f2bf(hi[0]); bf[5] = (short)f2bf(hi[1]);
        bf[6] = (short)f2bf(hi[2]); bf[7] = (short)f2bf(hi[3]);
        const int kk = (ks % 9) * 32 + (kg << 3);
        #pragma unroll
        for (int mt = 0; mt < 4; ++mt) {
            const bf16x8 af = *(const bf16x8*)&A[((mt << 4) + (lane & 15)) * LSTR + kk];
            acc[mt] = __builtin_amdgcn_mfma_f32_16x16x32_bf16(af, bf, acc[mt], 0, 0, 0);
        }
    }

    // epilogue: outT[hw][b*64+co] bf16, contiguous per block
    const int rg = lane >> 4;
    const size_t obase = (size_t)((h << 6) + wq) * 4096;
    #pragma unroll
    for (int mt = 0; mt < 4; ++mt) {
        #pragma unroll
        for (int j = 0; j < 4; ++j) {
            const int b = (mt << 4) + (rg << 2) + j;
            outT[obase + (b << 6) + co] = f2bf(fmaxf(acc[mt][j], 0.f));
        }
    }
}

// ---- Fallback (round-2 proven): direct gather + direct scattered write ----
__global__ __launch_bounds__(256, 4)
void lc_mfma(const float* __restrict__ x, const float* __restrict__ wt,
             float* __restrict__ out) {
    __shared__ __align__(16) unsigned short A[64 * LSTR];
    const int bid = blockIdx.x;
    const int swz = (bid & 7) * 512 + (bid >> 3);
    const int h   = swz >> 6;
    const int wq  = swz & 63;
    const int t    = threadIdx.x;
    const int lane = t & 63;
    const int wv   = t >> 6;
    const float* wloc = wt + (size_t)((h << 6) + wq) * 36864;
    const int co = (wv << 4) + (lane & 15);
    const int kg = lane >> 4;
    const float* wrow = wloc + co * 576 + (kg << 3);
    f32x4 acc[4] = {{0.f,0.f,0.f,0.f},{0.f,0.f,0.f,0.f},
                    {0.f,0.f,0.f,0.f},{0.f,0.f,0.f,0.f}};
    const int cil = t & 31;
    const int bro = t >> 5;
    for (int hs = 0; hs < 2; ++hs) {
        const int kbase = hs * 288;
        f32x4 pb[3][2];
        pb[0][0] = __builtin_nontemporal_load((const f32x4*)(wrow + kbase + 0));
        pb[0][1] = __builtin_nontemporal_load((const f32x4*)(wrow + kbase + 4));
        pb[1][0] = __builtin_nontemporal_load((const f32x4*)(wrow + kbase + 32));
        pb[1][1] = __builtin_nontemporal_load((const f32x4*)(wrow + kbase + 36));
        {
            const int ci = (hs << 5) + cil;
            for (int p = 0; p < 8; ++p) {
                const int b = (p << 3) + bro;
                const float* xb = x + ((size_t)((b << 6) + ci) << 12);
                unsigned short* dst = &A[b * LSTR + cil * 9];
                #pragma unroll
                for (int dy = 0; dy < 3; ++dy) {
                    const int y = h + dy - 1;
                    const bool yok = (unsigned)y < 64u;
                    #pragma unroll
                    for (int dx = 0; dx < 3; ++dx) {
                        const int xx = wq + dx - 1;
                        float v = 0.f;
                        if (yok && (unsigned)xx < 64u) v = xb[(y << 6) + xx];
                        dst[dy * 3 + dx] = f2bf(v);
                    }
                }
            }
        }
        __syncthreads();
        #pragma unroll
        for (int ks = 0; ks < 9; ++ks) {
            const int cur = ks % 3;
            const int nxt = (ks + 2) % 3;
            if (ks < 7) {
                const float* np = wrow + kbase + (ks + 2) * 32;
                pb[nxt][0] = __builtin_nontemporal_load((const f32x4*)(np));
                pb[nxt][1] = __builtin_nontemporal_load((const f32x4*)(np + 4));
            }
            const f32x4 lo = pb[cur][0], hi = pb[cur][1];
            bf16x8 bf;
            bf[0] = (short)f2bf(lo[0]); bf[1] = (short)f2bf(lo[1]);
            bf[2] = (short)f2bf(lo[2]); bf[3] = (short)f2bf(lo[3]);
            bf[4] = (short)f2bf(hi[0]); bf[5] = (short)f2bf(hi[1]);
            bf[6] = (short)f2bf(hi[2]); bf[7] = (short)f2bf(hi[3]);
            const int kk = (ks << 5) + (kg << 3);
            #pragma unroll
            for (int mt = 0; mt < 4; ++mt) {
                const bf16x8 af = *(const bf16x8*)&A[((mt << 4) + (lane & 15)) * LSTR + kk];
                acc[mt] = __builtin_amdgcn_mfma_f32_16x16x32_bf16(af, bf, acc[mt], 0, 0, 0);
            }
        }
        __syncthreads();
    }
    const int rg = lane >> 4;
    #pragma unroll
    for (int mt = 0; mt < 4; ++mt) {
        #pragma unroll
        for (int j = 0; j < 4; ++j) {
            const int b = (mt << 4) + (rg << 2) + j;
            out[(size_t)((b << 6) + co) * 4096 + (h << 6) + wq] = fmaxf(acc[mt][j], 0.f);
        }
    }
}

extern "C" void kernel_launch(void* const* d_in, const int* in_sizes, int n_in,
                              void* d_out, int out_size, void* d_ws, size_t ws_size,
                              hipStream_t stream) {
    const float* x  = (const float*)d_in[0];
    const float* wt = (const float*)d_in[1];
    float* out = (float*)d_out;

    const size_t xT_bytes   = (size_t)4096 * 4096 * 2;  // 33.5 MB bf16
    const size_t outT_bytes = (size_t)4096 * 4096 * 2;  // 33.5 MB bf16

    if (ws_size >= xT_bytes + outT_bytes) {
        unsigned short* xT   = (unsigned short*)d_ws;
        unsigned short* outT = (unsigned short*)((char*)d_ws + xT_bytes);
        hipLaunchKernelGGL(transpose_in, dim3(4096), dim3(256), 0, stream, x, xT);
        hipLaunchKernelGGL(lc_main, dim3(4096), dim3(256), 0, stream, xT, wt, outT);
        hipLaunchKernelGGL(transpose_out_bf, dim3(4096), dim3(256), 0, stream, outT, out);
    } else {
        hipLaunchKernelGGL(lc_mfma, dim3(4096), dim3(256), 0, stream, x, wt, out);
    }
}